// Round 9
// baseline (1131.583 us; speedup 1.0000x reference)
//
#include <hip/hip_runtime.h>
#include <hip/hip_bf16.h>

// 3-layer stacked LSTM forward (eval). Round 9 = Round 8 + LDS-only barriers.
//  The r8 profile showed per-step time ~3250cyc with everything idle: the
//  compiler's full drain (s_waitcnt vmcnt(0)) before every __syncthreads()
//  serialized global-store ack + defeated the x prefetch. In-loop barriers are
//  now raw `s_waitcnt lgkmcnt(0); s_barrier` (LDS ordering only; global stores
//  float; compiler still inserts counted vmcnt before prefetch use).
//  - scan1_fused: xacc = bias + x[t]*Wih (MFMA, 1 step ahead, 2-deep global
//    prefetch); preact = xacc + h*Whh (MFMA); i,f,g,o same lane; h -> swizzled
//    LDS + bf16 hout. Weights pinned in regs/AGPRs.
//  - scan23_fused: same for layer 2 (waves 0-3) + layer 3 on wave 4 (f32 LDS
//    h2 ring + h3*Whh3 recurrence, lanes 0-15).
// T=512, B=256, IN=97(pad128), H1=128, H2=64, H3=1.

#define T_TOT 512
#define BB    256

typedef __attribute__((ext_vector_type(8))) short  short8v;   // 8 bf16
typedef __attribute__((ext_vector_type(4))) float  float4v;   // MFMA acc

__device__ __forceinline__ void bar_lds() {
    // LDS-only barrier: order ds ops, do NOT drain vmcnt (global stores/loads
    // stay in flight across the barrier).
    asm volatile("s_waitcnt lgkmcnt(0)\n\ts_barrier" ::: "memory");
}

__device__ __forceinline__ float sigm(float x) {
    float e = __expf(-x);
    return __builtin_amdgcn_rcpf(1.0f + e);
}
__device__ __forceinline__ float tanh_(float x) {
    float e = __expf(2.0f * x);
    return 1.0f - 2.0f * __builtin_amdgcn_rcpf(1.0f + e);
}
__device__ __forceinline__ unsigned short f2bf(float x) {
    __hip_bfloat16 b = __float2bfloat16(x);
    return __builtin_bit_cast(unsigned short, b);
}

// ---------------------------------------------------------------------------
__global__ __launch_bounds__(256) void cvt_pad(
    const float* __restrict__ in, __hip_bfloat16* __restrict__ out, int R, int K)
{
    int total = R * 128;
    for (int idx = blockIdx.x * 256 + threadIdx.x; idx < total; idx += gridDim.x * 256) {
        int r = idx >> 7, c = idx & 127;
        float v = (c < K) ? in[(size_t)r * K + c] : 0.0f;
        out[idx] = __float2bfloat16(v);
    }
}
__global__ __launch_bounds__(256) void cvt_plain(
    const float* __restrict__ in, __hip_bfloat16* __restrict__ out, int n)
{
    int i = blockIdx.x * 256 + threadIdx.x;
    if (i < n) out[i] = __float2bfloat16(in[i]);
}
__global__ __launch_bounds__(256) void addvec(
    const float* __restrict__ a, const float* __restrict__ b, float* __restrict__ o, int n)
{
    int i = blockIdx.x * 256 + threadIdx.x;
    if (i < n) o[i] = a[i] + b[i];
}

// ---------------------------------------------------------------------------
// scan1_fused (H=128): 16 blocks x 512 thr (8 waves).
// ---------------------------------------------------------------------------
__global__ __launch_bounds__(512, 2) void scan1_fused(
    const __hip_bfloat16* __restrict__ xb,   // [T, BB, 128] bf16 (padded)
    const __hip_bfloat16* __restrict__ Wx,   // [512, 128] Wih1 bf16 (padded)
    const __hip_bfloat16* __restrict__ Wh,   // [512, 128] Whh1 bf16
    const float* __restrict__ bias,          // [512] bih1+bhh1
    __hip_bfloat16* __restrict__ hout)       // [T, BB, 128]
{
    const int tid  = threadIdx.x;
    const int lane = tid & 63;
    const int wid  = tid >> 6;
    const int br0  = blockIdx.x * 16;
    const int myu  = wid * 16 + (lane & 15);

    __shared__ __align__(16) char hb[2][4096];

    uint4 wfx[4][4], wfh[4][4];
    {
        const char* Wxg = (const char*)Wx;
        const char* Whg = (const char*)Wh;
#pragma unroll
        for (int G = 0; G < 4; ++G) {
            int row = G * 128 + myu;
#pragma unroll
            for (int kf = 0; kf < 4; ++kf) {
                int colb = (kf * 32 + (lane >> 4) * 8) * 2;
                wfx[G][kf] = *(const uint4*)(Wxg + (size_t)row * 256 + colb);
                wfh[G][kf] = *(const uint4*)(Whg + (size_t)row * 256 + colb);
            }
        }
    }
#pragma unroll
    for (int G = 0; G < 4; ++G)
#pragma unroll
        for (int kf = 0; kf < 4; ++kf) {
            asm volatile("" : "+v"(wfx[G][kf].x), "+v"(wfx[G][kf].y),
                              "+v"(wfx[G][kf].z), "+v"(wfx[G][kf].w));
            asm volatile("" : "+v"(wfh[G][kf].x), "+v"(wfh[G][kf].y),
                              "+v"(wfh[G][kf].z), "+v"(wfh[G][kf].w));
        }

    float bv[4];
#pragma unroll
    for (int G = 0; G < 4; ++G) bv[G] = bias[G * 128 + myu];

    float c[4] = {0.0f, 0.0f, 0.0f, 0.0f};

    ((unsigned int*)hb)[tid]       = 0u;
    ((unsigned int*)hb)[tid + 512] = 0u;
    __syncthreads();

    const char* xgb = (const char*)xb +
        ((size_t)(br0 + (lane & 15)) * 128 + (lane >> 4) * 8) * 2;
    const size_t XSTEP = (size_t)BB * 128 * 2;

    uint4 xafA[4], xafB[4];
#pragma unroll
    for (int kf = 0; kf < 4; ++kf) xafA[kf] = *(const uint4*)(xgb + kf * 64);
    float4v xacc[4];
#pragma unroll
    for (int G = 0; G < 4; ++G) {
        float4v t0 = {bv[G], bv[G], bv[G], bv[G]};
#pragma unroll
        for (int kf = 0; kf < 4; ++kf)
            t0 = __builtin_amdgcn_mfma_f32_16x16x32_bf16(
                __builtin_bit_cast(short8v, xafA[kf]),
                __builtin_bit_cast(short8v, wfx[G][kf]), t0, 0, 0, 0);
        xacc[G] = t0;
    }
#pragma unroll
    for (int kf = 0; kf < 4; ++kf) xafB[kf] = *(const uint4*)(xgb + XSTEP + kf * 64);

    int cur = 0;
    for (int t = 0; t < T_TOT; ++t) {
        short8v afh[4];
#pragma unroll
        for (int kf = 0; kf < 4; ++kf) {
            int row  = lane & 15;
            int byte = (row * 256 + kf * 64 + (lane >> 4) * 16) ^ ((row & 7) << 4);
            afh[kf] = *(const short8v*)(hb[cur] + byte);
        }
        float4v acc[4];
#pragma unroll
        for (int G = 0; G < 4; ++G) {
            float4v a = xacc[G];
#pragma unroll
            for (int kf = 0; kf < 4; ++kf)
                a = __builtin_amdgcn_mfma_f32_16x16x32_bf16(
                    afh[kf], __builtin_bit_cast(short8v, wfh[G][kf]), a, 0, 0, 0);
            acc[G] = a;
        }
#pragma unroll
        for (int kf = 0; kf < 4; ++kf) xafA[kf] = xafB[kf];
        if (t + 2 < T_TOT) {
            const char* xn = xgb + (size_t)(t + 2) * XSTEP;
#pragma unroll
            for (int kf = 0; kf < 4; ++kf) xafB[kf] = *(const uint4*)(xn + kf * 64);
        }
#pragma unroll
        for (int G = 0; G < 4; ++G) {
            float4v a = {bv[G], bv[G], bv[G], bv[G]};
#pragma unroll
            for (int kf = 0; kf < 4; ++kf)
                a = __builtin_amdgcn_mfma_f32_16x16x32_bf16(
                    __builtin_bit_cast(short8v, xafA[kf]),
                    __builtin_bit_cast(short8v, wfx[G][kf]), a, 0, 0, 0);
            xacc[G] = a;
        }
#pragma unroll
        for (int r = 0; r < 4; ++r) {
            float i_ = sigm(acc[0][r]);
            float f_ = sigm(acc[1][r]);
            float g_ = tanh_(acc[2][r]);
            float o_ = sigm(acc[3][r]);
            c[r] = fmaf(f_, c[r], i_ * g_);
            float h = o_ * tanh_(c[r]);
            unsigned short h16 = f2bf(h);
            int br   = (lane >> 4) * 4 + r;
            int byte = (br * 256 + myu * 2) ^ ((br & 7) << 4);
            *(unsigned short*)(hb[cur ^ 1] + byte) = h16;
            ((unsigned short*)hout)[((size_t)t * BB + br0 + br) * 128 + myu] = h16;
        }
        bar_lds();   // LDS-only: global stores + prefetch loads stay in flight
        cur ^= 1;
    }
}

// ---------------------------------------------------------------------------
// scan23_fused: 16 blocks x 320 thr (5 waves). Waves 0-3: layer 2. Wave 4:
// layer 3 (one step behind), including the h3*Whh3 recurrence term.
// ---------------------------------------------------------------------------
__global__ __launch_bounds__(320, 2) void scan23_fused(
    const __hip_bfloat16* __restrict__ h1b,  // [T, BB, 128]
    const __hip_bfloat16* __restrict__ Wx2,  // [256, 128] Wih2 bf16
    const __hip_bfloat16* __restrict__ Wh2,  // [256, 64]  Whh2 bf16
    const float* __restrict__ bias2,         // [256]
    const float* __restrict__ Wx3,           // [4, 64] f32 (raw input)
    const float* __restrict__ Wh3,           // [4, 1]  f32 (raw input)
    const float* __restrict__ bias3,         // [4]
    float* __restrict__ out)                 // [T, BB]
{
    const int tid  = threadIdx.x;
    const int lane = tid & 63;
    const int wid  = tid >> 6;     // 0..4
    const int br0  = blockIdx.x * 16;

    __shared__ __align__(16) char  h2b[2][2048];
    __shared__ __align__(16) float h2f[2][16][68];
    __shared__ float g3[64];

    if (wid < 4) {
        const int myu = wid * 16 + (lane & 15);

        uint4 wfx[4][4], wfh[4][2];
        {
            const char* Wxg = (const char*)Wx2;
            const char* Whg = (const char*)Wh2;
#pragma unroll
            for (int G = 0; G < 4; ++G) {
                int row = G * 64 + myu;
#pragma unroll
                for (int kf = 0; kf < 4; ++kf)
                    wfx[G][kf] = *(const uint4*)(Wxg + (size_t)row * 256 +
                                                 (kf * 32 + (lane >> 4) * 8) * 2);
#pragma unroll
                for (int kf = 0; kf < 2; ++kf)
                    wfh[G][kf] = *(const uint4*)(Whg + (size_t)row * 128 +
                                                 (kf * 32 + (lane >> 4) * 8) * 2);
            }
        }
#pragma unroll
        for (int G = 0; G < 4; ++G) {
#pragma unroll
            for (int kf = 0; kf < 4; ++kf)
                asm volatile("" : "+v"(wfx[G][kf].x), "+v"(wfx[G][kf].y),
                                  "+v"(wfx[G][kf].z), "+v"(wfx[G][kf].w));
#pragma unroll
            for (int kf = 0; kf < 2; ++kf)
                asm volatile("" : "+v"(wfh[G][kf].x), "+v"(wfh[G][kf].y),
                                  "+v"(wfh[G][kf].z), "+v"(wfh[G][kf].w));
        }

        float bv[4];
#pragma unroll
        for (int G = 0; G < 4; ++G) bv[G] = bias2[G * 64 + myu];

        float c[4] = {0.0f, 0.0f, 0.0f, 0.0f};

        ((unsigned int*)h2b)[tid]       = 0u;
        ((unsigned int*)h2b)[tid + 256] = 0u;
        {
            float* z = &h2f[0][0][0];
            for (int j = tid; j < 16 * 68; j += 256) z[j] = 0.0f;
        }

        const char* xgb = (const char*)h1b +
            ((size_t)(br0 + (lane & 15)) * 128 + (lane >> 4) * 8) * 2;
        const size_t XSTEP = (size_t)BB * 128 * 2;

        uint4 xafA[4], xafB[4];
#pragma unroll
        for (int kf = 0; kf < 4; ++kf) xafA[kf] = *(const uint4*)(xgb + kf * 64);
        float4v xacc[4];
#pragma unroll
        for (int G = 0; G < 4; ++G) {
            float4v t0 = {bv[G], bv[G], bv[G], bv[G]};
#pragma unroll
            for (int kf = 0; kf < 4; ++kf)
                t0 = __builtin_amdgcn_mfma_f32_16x16x32_bf16(
                    __builtin_bit_cast(short8v, xafA[kf]),
                    __builtin_bit_cast(short8v, wfx[G][kf]), t0, 0, 0, 0);
            xacc[G] = t0;
        }
#pragma unroll
        for (int kf = 0; kf < 4; ++kf) xafB[kf] = *(const uint4*)(xgb + XSTEP + kf * 64);

        __syncthreads();   // pre-loop barrier (matches wave4)

        for (int t = 0; t <= T_TOT; ++t) {
            if (t < T_TOT) {
                int cur = t & 1;
                short8v afh[2];
#pragma unroll
                for (int kf = 0; kf < 2; ++kf) {
                    int row  = lane & 15;
                    int byte = (row * 128 + kf * 64 + (lane >> 4) * 16) ^ ((row & 7) << 4);
                    afh[kf] = *(const short8v*)(h2b[cur] + byte);
                }
                float4v acc[4];
#pragma unroll
                for (int G = 0; G < 4; ++G) {
                    float4v a = xacc[G];
#pragma unroll
                    for (int kf = 0; kf < 2; ++kf)
                        a = __builtin_amdgcn_mfma_f32_16x16x32_bf16(
                            afh[kf], __builtin_bit_cast(short8v, wfh[G][kf]), a, 0, 0, 0);
                    acc[G] = a;
                }
#pragma unroll
                for (int kf = 0; kf < 4; ++kf) xafA[kf] = xafB[kf];
                if (t + 2 < T_TOT) {
                    const char* xn = xgb + (size_t)(t + 2) * XSTEP;
#pragma unroll
                    for (int kf = 0; kf < 4; ++kf) xafB[kf] = *(const uint4*)(xn + kf * 64);
                }
#pragma unroll
                for (int G = 0; G < 4; ++G) {
                    float4v a = {bv[G], bv[G], bv[G], bv[G]};
#pragma unroll
                    for (int kf = 0; kf < 4; ++kf)
                        a = __builtin_amdgcn_mfma_f32_16x16x32_bf16(
                            __builtin_bit_cast(short8v, xafA[kf]),
                            __builtin_bit_cast(short8v, wfx[G][kf]), a, 0, 0, 0);
                    xacc[G] = a;
                }
#pragma unroll
                for (int r = 0; r < 4; ++r) {
                    float i_ = sigm(acc[0][r]);
                    float f_ = sigm(acc[1][r]);
                    float g_ = tanh_(acc[2][r]);
                    float o_ = sigm(acc[3][r]);
                    c[r] = fmaf(f_, c[r], i_ * g_);
                    float h = o_ * tanh_(c[r]);
                    int br   = (lane >> 4) * 4 + r;
                    int byte = (br * 128 + myu * 2) ^ ((br & 7) << 4);
                    *(unsigned short*)(h2b[cur ^ 1] + byte) = f2bf(h);
                    h2f[cur ^ 1][br][myu] = h;
                }
            }
            bar_lds();
        }
    } else {
        // ---- wave 4: layer 3 (H=1), one step behind ----
        const int row  = lane >> 2;     // 0..15
        const int gate = lane & 3;
        float4 w3[16];
        {
            const float4* w3p = (const float4*)(Wx3 + gate * 64);
#pragma unroll
            for (int j = 0; j < 16; ++j) w3[j] = w3p[j];
        }
        float bv3 = bias3[gate];
        float c3 = 0.0f, h3 = 0.0f;
        const float w30 = Wh3[0], w31 = Wh3[1], w32 = Wh3[2], w33 = Wh3[3];

        __syncthreads();   // pre-loop barrier

        for (int t = 0; t <= T_TOT; ++t) {
            if (t >= 1) {
                const float* hrow = &h2f[t & 1][row][0];
                float a = bv3;
#pragma unroll
                for (int j = 0; j < 16; ++j) {
                    float4 hv = ((const float4*)hrow)[j];
                    float4 wv = w3[j];
                    a = fmaf(hv.x, wv.x, a);
                    a = fmaf(hv.y, wv.y, a);
                    a = fmaf(hv.z, wv.z, a);
                    a = fmaf(hv.w, wv.w, a);
                }
                g3[lane] = a;
                if (lane < 16) {
                    float4 gg = *(const float4*)(g3 + lane * 4);
                    float gi  = fmaf(h3, w30, gg.x);
                    float gf  = fmaf(h3, w31, gg.y);
                    float gg_ = fmaf(h3, w32, gg.z);
                    float go  = fmaf(h3, w33, gg.w);
                    float i_ = sigm(gi);
                    float f_ = sigm(gf);
                    float g_ = tanh_(gg_);
                    float o_ = sigm(go);
                    c3 = fmaf(f_, c3, i_ * g_);
                    h3 = o_ * tanh_(c3);
                    out[(size_t)(t - 1) * BB + br0 + lane] = h3;
                }
            }
            bar_lds();
        }
    }
}

// ---------------------------------------------------------------------------
extern "C" void kernel_launch(void* const* d_in, const int* in_sizes, int n_in,
                              void* d_out, int out_size, void* d_ws, size_t ws_size,
                              hipStream_t stream) {
    const float* x    = (const float*)d_in[0];
    const float* Wih1 = (const float*)d_in[1];
    const float* Whh1 = (const float*)d_in[2];
    const float* bih1 = (const float*)d_in[3];
    const float* bhh1 = (const float*)d_in[4];
    const float* Wih2 = (const float*)d_in[5];
    const float* Whh2 = (const float*)d_in[6];
    const float* bih2 = (const float*)d_in[7];
    const float* bhh2 = (const float*)d_in[8];
    const float* Wih3 = (const float*)d_in[9];
    const float* Whh3 = (const float*)d_in[10];
    const float* bih3 = (const float*)d_in[11];
    const float* bhh3 = (const float*)d_in[12];
    float* out = (float*)d_out;

    char* ws = (char*)d_ws;
    __hip_bfloat16* xb    = (__hip_bfloat16*)(ws + 0);          // 33,554,432
    __hip_bfloat16* h1b   = (__hip_bfloat16*)(ws + 33554432);   // 33,554,432
    __hip_bfloat16* wb1   = (__hip_bfloat16*)(ws + 67108864);   //    131,072
    __hip_bfloat16* whb1  = (__hip_bfloat16*)(ws + 67239936);   //    131,072
    __hip_bfloat16* wb2   = (__hip_bfloat16*)(ws + 67371008);   //     65,536
    __hip_bfloat16* whb2  = (__hip_bfloat16*)(ws + 67436544);   //     32,768
    float*          bias1 = (float*)(ws + 67469312);            //      2,048
    float*          bias2 = (float*)(ws + 67471360);            //      1,024
    float*          bias3 = (float*)(ws + 67472384);            //         16

    cvt_pad<<<4096, 256, 0, stream>>>(x, xb, T_TOT * BB, 97);
    cvt_pad<<<256, 256, 0, stream>>>(Wih1, wb1, 512, 97);
    cvt_plain<<<256, 256, 0, stream>>>(Whh1, whb1, 512 * 128);
    cvt_plain<<<128, 256, 0, stream>>>(Wih2, wb2, 256 * 128);
    cvt_plain<<<64, 256, 0, stream>>>(Whh2, whb2, 256 * 64);
    addvec<<<2, 256, 0, stream>>>(bih1, bhh1, bias1, 512);
    addvec<<<1, 256, 0, stream>>>(bih2, bhh2, bias2, 256);
    addvec<<<1, 256, 0, stream>>>(bih3, bhh3, bias3, 4);

    scan1_fused<<<16, 512, 0, stream>>>(xb, wb1, whb1, bias1, h1b);
    scan23_fused<<<16, 320, 0, stream>>>(h1b, wb2, whb2, bias2, Wih3, Whh3, bias3, out);
}

// Round 10
// 872.539 us; speedup vs baseline: 1.2969x; 1.2969x over previous
//
#include <hip/hip_runtime.h>
#include <hip/hip_bf16.h>

// 3-layer stacked LSTM forward (eval). Round 10:
//  - ONE fused kernel, 32 blocks: blocks 0-15 = layer-1 producer, blocks 16-31 =
//    layer-2+3 consumer. Producer block b writes h1[t] rows [16b,16b+16) and
//    publishes flags[b] every 8 steps (vmcnt drain + threadfence + agent atomic);
//    consumer block 16+b polls flags[b] with a 16-step margin. No deadlock:
//    producer never waits; 32 blocks co-resident. Flags zeroed per launch.
//  - Per-step VALU cuts vs r9: in-place h-MFMA into xacc (kills a=xacc copy),
//    2-step unroll alternating x prefetch bufs (kills xafA=xafB copy), hout via
//    coalesced LDS->global dword flush (replaces 4 scattered 2B stores).
//  - Math identical to r9: absmax must stay exactly 0.001953125.
// T=512, B=256, IN=97(pad128), H1=128, H2=64, H3=1.

#define T_TOT 512
#define BB    256

typedef __attribute__((ext_vector_type(8))) short  short8v;   // 8 bf16
typedef __attribute__((ext_vector_type(4))) float  float4v;   // MFMA acc

__device__ __forceinline__ void bar_lds() {
    asm volatile("s_waitcnt lgkmcnt(0)\n\ts_barrier" ::: "memory");
}
__device__ __forceinline__ void bar_full() {
    asm volatile("s_waitcnt vmcnt(0) lgkmcnt(0)\n\ts_barrier" ::: "memory");
}

__device__ __forceinline__ float sigm(float x) {
    float e = __expf(-x);
    return __builtin_amdgcn_rcpf(1.0f + e);
}
__device__ __forceinline__ float tanh_(float x) {
    float e = __expf(2.0f * x);
    return 1.0f - 2.0f * __builtin_amdgcn_rcpf(1.0f + e);
}
__device__ __forceinline__ unsigned short f2bf(float x) {
    __hip_bfloat16 b = __float2bfloat16(x);
    return __builtin_bit_cast(unsigned short, b);
}

// ---------------------------------------------------------------------------
__global__ __launch_bounds__(256) void cvt_pad(
    const float* __restrict__ in, __hip_bfloat16* __restrict__ out, int R, int K)
{
    int total = R * 128;
    for (int idx = blockIdx.x * 256 + threadIdx.x; idx < total; idx += gridDim.x * 256) {
        int r = idx >> 7, c = idx & 127;
        float v = (c < K) ? in[(size_t)r * K + c] : 0.0f;
        out[idx] = __float2bfloat16(v);
    }
}
__global__ __launch_bounds__(256) void cvt_plain(
    const float* __restrict__ in, __hip_bfloat16* __restrict__ out, int n)
{
    int i = blockIdx.x * 256 + threadIdx.x;
    if (i < n) out[i] = __float2bfloat16(in[i]);
}
__global__ __launch_bounds__(256) void addvec(
    const float* __restrict__ a, const float* __restrict__ b, float* __restrict__ o, int n)
{
    int i = blockIdx.x * 256 + threadIdx.x;
    if (i < n) o[i] = a[i] + b[i];
}
__global__ void zero_flags(unsigned int* f) { f[threadIdx.x] = 0u; }

// ---------------------------------------------------------------------------
// Fused 3-layer kernel. 32 blocks x 512 threads.
// ---------------------------------------------------------------------------
__global__ __launch_bounds__(512, 2) void lstm_all(
    const __hip_bfloat16* __restrict__ xb,    // [T,BB,128]
    const __hip_bfloat16* __restrict__ Wx1,   // [512,128]
    const __hip_bfloat16* __restrict__ Wh1,   // [512,128]
    const float* __restrict__ bias1,          // [512]
    __hip_bfloat16* __restrict__ h1b,         // [T,BB,128]
    const __hip_bfloat16* __restrict__ Wx2,   // [256,128]
    const __hip_bfloat16* __restrict__ Wh2,   // [256,64]
    const float* __restrict__ bias2,          // [256]
    const float* __restrict__ Wx3,            // [4,64] f32
    const float* __restrict__ Wh3,            // [4,1]  f32
    const float* __restrict__ bias3,          // [4]
    float* __restrict__ out,                  // [T,BB]
    unsigned int* __restrict__ flags)         // [32]
{
    const int tid  = threadIdx.x;
    const int lane = tid & 63;
    const int wid  = tid >> 6;
    const int bid  = blockIdx.x;

    __shared__ __align__(16) char  hbP[2][4096];   // producer h ring (bf16, swz)
    __shared__ __align__(16) char  h2b[2][2048];   // consumer h2 ring (bf16, swz)
    __shared__ __align__(16) float h2f[2][16][68]; // consumer h2 ring (f32, for L3)
    __shared__ float g3[64];

    if (bid < 16) {
        // ================= PRODUCER: layer 1 =================
        const int br0 = bid * 16;
        const int myu = wid * 16 + (lane & 15);

        uint4 wfx[4][4], wfh[4][4];
        {
            const char* Wxg = (const char*)Wx1;
            const char* Whg = (const char*)Wh1;
#pragma unroll
            for (int G = 0; G < 4; ++G) {
                int row = G * 128 + myu;
#pragma unroll
                for (int kf = 0; kf < 4; ++kf) {
                    int colb = (kf * 32 + (lane >> 4) * 8) * 2;
                    wfx[G][kf] = *(const uint4*)(Wxg + (size_t)row * 256 + colb);
                    wfh[G][kf] = *(const uint4*)(Whg + (size_t)row * 256 + colb);
                }
            }
        }
#pragma unroll
        for (int G = 0; G < 4; ++G)
#pragma unroll
            for (int kf = 0; kf < 4; ++kf) {
                asm volatile("" : "+v"(wfx[G][kf].x), "+v"(wfx[G][kf].y),
                                  "+v"(wfx[G][kf].z), "+v"(wfx[G][kf].w));
                asm volatile("" : "+v"(wfh[G][kf].x), "+v"(wfh[G][kf].y),
                                  "+v"(wfh[G][kf].z), "+v"(wfh[G][kf].w));
            }

        float bv[4];
#pragma unroll
        for (int G = 0; G < 4; ++G) bv[G] = bias1[G * 128 + myu];
        float c[4] = {0.0f, 0.0f, 0.0f, 0.0f};

        ((unsigned int*)hbP)[tid]       = 0u;
        ((unsigned int*)hbP)[tid + 512] = 0u;

        // static LDS byte offsets
        int hrd[4];
#pragma unroll
        for (int kf = 0; kf < 4; ++kf) {
            int row = lane & 15;
            hrd[kf] = (row * 256 + kf * 64 + (lane >> 4) * 16) ^ ((row & 7) << 4);
        }
        int hwr[4];
#pragma unroll
        for (int r = 0; r < 4; ++r) {
            int br = (lane >> 4) * 4 + r;
            hwr[r] = (br * 256 + myu * 2) ^ ((br & 7) << 4);
        }
        const int row0 = tid >> 6;                       // flush row (0..7)
        const int fl0  = (tid * 4) ^ ((row0 & 7) << 4);  // (+2048 for row0+8)

        const char* xgb = (const char*)xb +
            ((size_t)(br0 + (lane & 15)) * 128 + (lane >> 4) * 8) * 2;
        const char* xp = xgb + 2 * 65536;                // next load target: t=2
        char* hp = (char*)h1b + (size_t)(br0 + row0) * 256 + (tid & 63) * 4;

        __syncthreads();

        // prologue: xacc = bias + x[0]*Wx ; xB <- x[1]
        uint4 xA[4], xB[4];
#pragma unroll
        for (int kf = 0; kf < 4; ++kf) xA[kf] = *(const uint4*)(xgb + kf * 64);
        float4v xacc[4];
#pragma unroll
        for (int G = 0; G < 4; ++G) {
            float4v a = {bv[G], bv[G], bv[G], bv[G]};
#pragma unroll
            for (int kf = 0; kf < 4; ++kf)
                a = __builtin_amdgcn_mfma_f32_16x16x32_bf16(
                    __builtin_bit_cast(short8v, xA[kf]),
                    __builtin_bit_cast(short8v, wfx[G][kf]), a, 0, 0, 0);
            xacc[G] = a;
        }
#pragma unroll
        for (int kf = 0; kf < 4; ++kf) xB[kf] = *(const uint4*)(xgb + 65536 + kf * 64);

#define PSTEP(T, CUR, USE, LOAD) do {                                          \
        if ((T) > 0) {                                                         \
            unsigned int d0 = *(const unsigned int*)(&hbP[CUR][0] + fl0);      \
            unsigned int d1 = *(const unsigned int*)(&hbP[CUR][0] + fl0 + 2048);\
            *(unsigned int*)hp = d0;                                           \
            *(unsigned int*)(hp + 2048) = d1;                                  \
            hp += 65536;                                                       \
        }                                                                      \
        short8v afh[4];                                                        \
        afh[0] = *(const short8v*)(&hbP[CUR][0] + hrd[0]);                     \
        afh[1] = *(const short8v*)(&hbP[CUR][0] + hrd[1]);                     \
        afh[2] = *(const short8v*)(&hbP[CUR][0] + hrd[2]);                     \
        afh[3] = *(const short8v*)(&hbP[CUR][0] + hrd[3]);                     \
        _Pragma("unroll")                                                      \
        for (int G = 0; G < 4; ++G)                                            \
            _Pragma("unroll")                                                  \
            for (int kf = 0; kf < 4; ++kf)                                     \
                xacc[G] = __builtin_amdgcn_mfma_f32_16x16x32_bf16(             \
                    afh[kf], __builtin_bit_cast(short8v, wfh[G][kf]),          \
                    xacc[G], 0, 0, 0);                                         \
        _Pragma("unroll")                                                      \
        for (int r = 0; r < 4; ++r) {                                          \
            float i_ = sigm(xacc[0][r]);                                       \
            float f_ = sigm(xacc[1][r]);                                       \
            float g_ = tanh_(xacc[2][r]);                                      \
            float o_ = sigm(xacc[3][r]);                                       \
            c[r] = fmaf(f_, c[r], i_ * g_);                                    \
            float hv = o_ * tanh_(c[r]);                                       \
            *(unsigned short*)(&hbP[(CUR) ^ 1][0] + hwr[r]) = f2bf(hv);        \
        }                                                                      \
        if ((T) + 1 < T_TOT) {                                                 \
            _Pragma("unroll")                                                  \
            for (int G = 0; G < 4; ++G) {                                      \
                float4v a = {bv[G], bv[G], bv[G], bv[G]};                      \
                _Pragma("unroll")                                              \
                for (int kf = 0; kf < 4; ++kf)                                 \
                    a = __builtin_amdgcn_mfma_f32_16x16x32_bf16(               \
                        __builtin_bit_cast(short8v, USE[kf]),                  \
                        __builtin_bit_cast(short8v, wfx[G][kf]), a, 0, 0, 0);  \
                xacc[G] = a;                                                   \
            }                                                                  \
        }                                                                      \
        if ((T) + 2 < T_TOT) {                                                 \
            LOAD[0] = *(const uint4*)(xp + 0);                                 \
            LOAD[1] = *(const uint4*)(xp + 64);                                \
            LOAD[2] = *(const uint4*)(xp + 128);                               \
            LOAD[3] = *(const uint4*)(xp + 192);                               \
            xp += 65536;                                                       \
        }                                                                      \
        bar_lds();                                                             \
    } while (0)

        for (int t0 = 0; t0 < T_TOT; t0 += 8) {
#pragma unroll
            for (int u = 0; u < 8; u += 2) {
                PSTEP(t0 + u,     0, xB, xA);
                PSTEP(t0 + u + 1, 1, xA, xB);
            }
            // publish: hout flushed through step t0+6 at this point
            bar_full();
            if (tid == 0) {
                __threadfence();
                __hip_atomic_store(&flags[bid], (unsigned int)(t0 / 8 + 1),
                                   __ATOMIC_RELEASE, __HIP_MEMORY_SCOPE_AGENT);
            }
        }
        // final flush of step 511 (h state in hbP[0])
        {
            unsigned int d0 = *(const unsigned int*)(&hbP[0][0] + fl0);
            unsigned int d1 = *(const unsigned int*)(&hbP[0][0] + fl0 + 2048);
            *(unsigned int*)hp = d0;
            *(unsigned int*)(hp + 2048) = d1;
        }
        asm volatile("s_waitcnt vmcnt(0)" ::: "memory");
        __syncthreads();
        if (tid == 0) {
            __threadfence();
            __hip_atomic_store(&flags[bid], 1u << 20,
                               __ATOMIC_RELEASE, __HIP_MEMORY_SCOPE_AGENT);
        }
#undef PSTEP

    } else {
        // ================= CONSUMER: layers 2+3 =================
        const int cbid = bid - 16;
        const int br0  = cbid * 16;
        const int myu  = wid * 16 + (lane & 15);     // meaningful for wid<4
        unsigned int* flagp = &flags[cbid];

        // ---- L2 state (wid<4) ----
        uint4 wfx2[4][4], wfh2[4][2];
        float bv2[4];
        float c2[4] = {0.0f, 0.0f, 0.0f, 0.0f};
        int hrd2[2], hwr2[4];
        // ---- L3 state (wid==4) ----
        float4 w3[16];
        float bv3 = 0.0f, c3 = 0.0f, h3 = 0.0f;
        float w30 = 0.0f, w31 = 0.0f, w32 = 0.0f, w33 = 0.0f;
        float* outp = out + br0 + lane;

        if (wid < 4) {
            const char* Wxg = (const char*)Wx2;
            const char* Whg = (const char*)Wh2;
#pragma unroll
            for (int G = 0; G < 4; ++G) {
                int row = G * 64 + myu;
#pragma unroll
                for (int kf = 0; kf < 4; ++kf)
                    wfx2[G][kf] = *(const uint4*)(Wxg + (size_t)row * 256 +
                                                  (kf * 32 + (lane >> 4) * 8) * 2);
#pragma unroll
                for (int kf = 0; kf < 2; ++kf)
                    wfh2[G][kf] = *(const uint4*)(Whg + (size_t)row * 128 +
                                                  (kf * 32 + (lane >> 4) * 8) * 2);
            }
#pragma unroll
            for (int G = 0; G < 4; ++G) {
#pragma unroll
                for (int kf = 0; kf < 4; ++kf)
                    asm volatile("" : "+v"(wfx2[G][kf].x), "+v"(wfx2[G][kf].y),
                                      "+v"(wfx2[G][kf].z), "+v"(wfx2[G][kf].w));
#pragma unroll
                for (int kf = 0; kf < 2; ++kf)
                    asm volatile("" : "+v"(wfh2[G][kf].x), "+v"(wfh2[G][kf].y),
                                      "+v"(wfh2[G][kf].z), "+v"(wfh2[G][kf].w));
            }
#pragma unroll
            for (int G = 0; G < 4; ++G) bv2[G] = bias2[G * 64 + myu];
#pragma unroll
            for (int kf = 0; kf < 2; ++kf) {
                int row = lane & 15;
                hrd2[kf] = (row * 128 + kf * 64 + (lane >> 4) * 16) ^ ((row & 7) << 4);
            }
#pragma unroll
            for (int r = 0; r < 4; ++r) {
                int br = (lane >> 4) * 4 + r;
                hwr2[r] = (br * 128 + myu * 2) ^ ((br & 7) << 4);
            }
        } else if (wid == 4) {
            const int gate = lane & 3;
            const float4* w3p = (const float4*)(Wx3 + gate * 64);
#pragma unroll
            for (int j = 0; j < 16; ++j) w3[j] = w3p[j];
            bv3 = bias3[gate];
            w30 = Wh3[0]; w31 = Wh3[1]; w32 = Wh3[2]; w33 = Wh3[3];
        }

        if (tid < 512) ((unsigned int*)h2b)[tid] = 0u;   // zero slot 0 (2048B)

        // pre-loop poll: need h1 through step 15 before prologue loads (t=0,1)
        if (tid == 0) {
            while (__hip_atomic_load(flagp, __ATOMIC_ACQUIRE,
                                     __HIP_MEMORY_SCOPE_AGENT) * 8u < 16u)
                __builtin_amdgcn_s_sleep(16);
        }
        __syncthreads();
        __threadfence();

        const char* xgb = (const char*)h1b +
            ((size_t)(br0 + (lane & 15)) * 128 + (lane >> 4) * 8) * 2;
        const char* xp2 = xgb + 2 * 65536;
        uint4 xA[4], xB[4];
        float4v xacc2[4];
        if (wid < 4) {
#pragma unroll
            for (int kf = 0; kf < 4; ++kf) xA[kf] = *(const uint4*)(xgb + kf * 64);
#pragma unroll
            for (int G = 0; G < 4; ++G) {
                float4v a = {bv2[G], bv2[G], bv2[G], bv2[G]};
#pragma unroll
                for (int kf = 0; kf < 4; ++kf)
                    a = __builtin_amdgcn_mfma_f32_16x16x32_bf16(
                        __builtin_bit_cast(short8v, xA[kf]),
                        __builtin_bit_cast(short8v, wfx2[G][kf]), a, 0, 0, 0);
            xacc2[G] = a;
            }
#pragma unroll
            for (int kf = 0; kf < 4; ++kf) xB[kf] = *(const uint4*)(xgb + 65536 + kf * 64);
        }
        __syncthreads();

#define CSTEP(T, CUR, USE, LOAD) do {                                          \
        if (wid < 4) {                                                         \
            short8v afh2[2];                                                   \
            afh2[0] = *(const short8v*)(&h2b[CUR][0] + hrd2[0]);               \
            afh2[1] = *(const short8v*)(&h2b[CUR][0] + hrd2[1]);               \
            _Pragma("unroll")                                                  \
            for (int G = 0; G < 4; ++G)                                        \
                _Pragma("unroll")                                              \
                for (int kf = 0; kf < 2; ++kf)                                 \
                    xacc2[G] = __builtin_amdgcn_mfma_f32_16x16x32_bf16(        \
                        afh2[kf], __builtin_bit_cast(short8v, wfh2[G][kf]),    \
                        xacc2[G], 0, 0, 0);                                    \
            _Pragma("unroll")                                                  \
            for (int r = 0; r < 4; ++r) {                                      \
                float i_ = sigm(xacc2[0][r]);                                  \
                float f_ = sigm(xacc2[1][r]);                                  \
                float g_ = tanh_(xacc2[2][r]);                                 \
                float o_ = sigm(xacc2[3][r]);                                  \
                c2[r] = fmaf(f_, c2[r], i_ * g_);                              \
                float hv = o_ * tanh_(c2[r]);                                  \
                *(unsigned short*)(&h2b[(CUR) ^ 1][0] + hwr2[r]) = f2bf(hv);   \
                h2f[(CUR) ^ 1][(lane >> 4) * 4 + r][myu] = hv;                 \
            }                                                                  \
            if ((T) + 1 < T_TOT) {                                             \
                _Pragma("unroll")                                              \
                for (int G = 0; G < 4; ++G) {                                  \
                    float4v a = {bv2[G], bv2[G], bv2[G], bv2[G]};              \
                    _Pragma("unroll")                                          \
                    for (int kf = 0; kf < 4; ++kf)                             \
                        a = __builtin_amdgcn_mfma_f32_16x16x32_bf16(           \
                            __builtin_bit_cast(short8v, USE[kf]),              \
                            __builtin_bit_cast(short8v, wfx2[G][kf]),          \
                            a, 0, 0, 0);                                       \
                    xacc2[G] = a;                                              \
                }                                                              \
            }                                                                  \
            if ((T) + 2 < T_TOT) {                                             \
                LOAD[0] = *(const uint4*)(xp2 + 0);                            \
                LOAD[1] = *(const uint4*)(xp2 + 64);                           \
                LOAD[2] = *(const uint4*)(xp2 + 128);                          \
                LOAD[3] = *(const uint4*)(xp2 + 192);                          \
                xp2 += 65536;                                                  \
            }                                                                  \
        } else if (wid == 4) {                                                 \
            if ((T) >= 1) {                                                    \
                const float* hrow = &h2f[CUR][lane >> 2][0];                   \
                float a = bv3;                                                 \
                _Pragma("unroll")                                              \
                for (int j = 0; j < 16; ++j) {                                 \
                    float4 hv = ((const float4*)hrow)[j];                      \
                    float4 wv = w3[j];                                         \
                    a = fmaf(hv.x, wv.x, a);                                   \
                    a = fmaf(hv.y, wv.y, a);                                   \
                    a = fmaf(hv.z, wv.z, a);                                   \
                    a = fmaf(hv.w, wv.w, a);                                   \
                }                                                              \
                g3[lane] = a;                                                  \
                if (lane < 16) {                                               \
                    float4 gg = *(const float4*)(g3 + lane * 4);               \
                    float gi  = fmaf(h3, w30, gg.x);                           \
                    float gf  = fmaf(h3, w31, gg.y);                           \
                    float gg_ = fmaf(h3, w32, gg.z);                           \
                    float go  = fmaf(h3, w33, gg.w);                           \
                    float i_ = sigm(gi);                                       \
                    float f_ = sigm(gf);                                       \
                    float g_ = tanh_(gg_);                                     \
                    float o_ = sigm(go);                                       \
                    c3 = fmaf(f_, c3, i_ * g_);                                \
                    h3 = o_ * tanh_(c3);                                       \
                    *outp = h3;                                                \
                }                                                              \
                outp += BB;                                                    \
            }                                                                  \
        }                                                                      \
        bar_lds();                                                             \
    } while (0)

        for (int t0 = 0; t0 < T_TOT; t0 += 8) {
            if (t0 > 0) {
                if (tid == 0) {
                    unsigned int need = (unsigned int)(t0 + 16);
                    while (__hip_atomic_load(flagp, __ATOMIC_ACQUIRE,
                                             __HIP_MEMORY_SCOPE_AGENT) * 8u < need)
                        __builtin_amdgcn_s_sleep(16);
                }
                bar_lds();
                __threadfence();
            }
#pragma unroll
            for (int u = 0; u < 8; u += 2) {
                CSTEP(t0 + u,     0, xB, xA);
                CSTEP(t0 + u + 1, 1, xA, xB);
            }
        }
        // tail: L3 step for t=512 (reads h2f[0], written at t=511)
        if (wid == 4) {
            const float* hrow = &h2f[0][lane >> 2][0];
            float a = bv3;
#pragma unroll
            for (int j = 0; j < 16; ++j) {
                float4 hv = ((const float4*)hrow)[j];
                float4 wv = w3[j];
                a = fmaf(hv.x, wv.x, a);
                a = fmaf(hv.y, wv.y, a);
                a = fmaf(hv.z, wv.z, a);
                a = fmaf(hv.w, wv.w, a);
            }
            g3[lane] = a;
            if (lane < 16) {
                float4 gg = *(const float4*)(g3 + lane * 4);
                float gi  = fmaf(h3, w30, gg.x);
                float gf  = fmaf(h3, w31, gg.y);
                float gg_ = fmaf(h3, w32, gg.z);
                float go  = fmaf(h3, w33, gg.w);
                float i_ = sigm(gi);
                float f_ = sigm(gf);
                float g_ = tanh_(gg_);
                float o_ = sigm(go);
                c3 = fmaf(f_, c3, i_ * g_);
                h3 = o_ * tanh_(c3);
                *outp = h3;
            }
        }
#undef CSTEP
    }
}

// ---------------------------------------------------------------------------
extern "C" void kernel_launch(void* const* d_in, const int* in_sizes, int n_in,
                              void* d_out, int out_size, void* d_ws, size_t ws_size,
                              hipStream_t stream) {
    const float* x    = (const float*)d_in[0];
    const float* Wih1 = (const float*)d_in[1];
    const float* Whh1 = (const float*)d_in[2];
    const float* bih1 = (const float*)d_in[3];
    const float* bhh1 = (const float*)d_in[4];
    const float* Wih2 = (const float*)d_in[5];
    const float* Whh2 = (const float*)d_in[6];
    const float* bih2 = (const float*)d_in[7];
    const float* bhh2 = (const float*)d_in[8];
    const float* Wih3 = (const float*)d_in[9];
    const float* Whh3 = (const float*)d_in[10];
    const float* bih3 = (const float*)d_in[11];
    const float* bhh3 = (const float*)d_in[12];
    float* out = (float*)d_out;

    char* ws = (char*)d_ws;
    __hip_bfloat16* xb    = (__hip_bfloat16*)(ws + 0);          // 33,554,432
    __hip_bfloat16* h1b   = (__hip_bfloat16*)(ws + 33554432);   // 33,554,432
    __hip_bfloat16* wb1   = (__hip_bfloat16*)(ws + 67108864);   //    131,072
    __hip_bfloat16* whb1  = (__hip_bfloat16*)(ws + 67239936);   //    131,072
    __hip_bfloat16* wb2   = (__hip_bfloat16*)(ws + 67371008);   //     65,536
    __hip_bfloat16* whb2  = (__hip_bfloat16*)(ws + 67436544);   //     32,768
    float*          bias1 = (float*)(ws + 67469312);            //      2,048
    float*          bias2 = (float*)(ws + 67471360);            //      1,024
    float*          bias3 = (float*)(ws + 67472384);            //         64
    unsigned int*   flags = (unsigned int*)(ws + 67472448);     //        128

    zero_flags<<<1, 32, 0, stream>>>(flags);
    cvt_pad<<<4096, 256, 0, stream>>>(x, xb, T_TOT * BB, 97);
    cvt_pad<<<256, 256, 0, stream>>>(Wih1, wb1, 512, 97);
    cvt_plain<<<256, 256, 0, stream>>>(Whh1, whb1, 512 * 128);
    cvt_plain<<<128, 256, 0, stream>>>(Wih2, wb2, 256 * 128);
    cvt_plain<<<64, 256, 0, stream>>>(Whh2, whb2, 256 * 64);
    addvec<<<2, 256, 0, stream>>>(bih1, bhh1, bias1, 512);
    addvec<<<1, 256, 0, stream>>>(bih2, bhh2, bias2, 256);
    addvec<<<1, 256, 0, stream>>>(bih3, bhh3, bias3, 4);

    lstm_all<<<32, 512, 0, stream>>>(
        xb, wb1, whb1, bias1, h1b,
        wb2, whb2, bias2, Wih3, Whh3, bias3, out, flags);
}